// Round 8
// baseline (493.936 us; speedup 1.0000x reference)
//
#include <hip/hip_runtime.h>

// LSTM round 8: single-wave ILP-2. B=8192, T=512, IN=5, H=32.
// 1024 blocks x 64 thr = 1 wave/SIMD (exact fill). Each wave runs TWO
// independent 4-batch groups (register-disjoint chains, shared weights) so the
// scheduler hides one chain's latency with the other's instructions.
// Per group: gates_T[128][16 cols = 4 batches dup4] via 24 mfma_16x16x32_bf16
// (Whh hi/lo + Wx/bias); lane owns 2 cells/group (all 4 gates in-lane).
// Transc cut 10->8 per cell via paired reciprocals. No LDS, no barriers.

typedef __attribute__((ext_vector_type(8))) short short8;
typedef __attribute__((ext_vector_type(4))) float f32x4;
typedef __attribute__((ext_vector_type(4))) unsigned int u32x4;

static constexpr int BB  = 8192;
static constexpr int TT  = 512;
static constexpr int NIN = 5;
static constexpr int HH  = 32;
static constexpr float K1 = 1.4426950408889634f;   // log2(e)
static constexpr float K2 = 2.8853900817779268f;   // 2*log2(e)

__device__ __forceinline__ unsigned short bf_rne(float f) {
    unsigned int u = __float_as_uint(f);
    u = (u + 0x7FFFu + ((u >> 16) & 1u)) >> 16;
    return (unsigned short)u;
}
__device__ __forceinline__ float bf_f32(unsigned short h) {
    return __uint_as_float((unsigned int)h << 16);
}
__device__ __forceinline__ unsigned int cvt_pk_bf16(float a, float b) {
    unsigned int r;
    asm("v_cvt_pk_bf16_f32 %0, %1, %2" : "=v"(r) : "v"(a), "v"(b));
    return r;
}

__global__ __launch_bounds__(64, 1) void lstm_ilp2(
    const float* __restrict__ x,     // [B, T, 5]
    const float* __restrict__ W_ih,  // [128, 5]
    const float* __restrict__ W_hh,  // [128, 32]
    const float* __restrict__ b_ih,  // [128]
    const float* __restrict__ b_hh,  // [128]
    const float* __restrict__ W_fc,  // [1, 32]
    const float* __restrict__ b_fc,  // [1]
    float* __restrict__ out)         // [B]
{
    const int lane = threadIdx.x & 63;
    const int col  = lane & 15;
    const int kg   = lane >> 4;
    const int bloc = col & 3;        // batch within group (cols dup 4x)
    const int q    = col >> 2;       // (jsel, rp) selector
    const bool jsel = (q & 1);
    const bool rp   = (q >> 1);
    const int b0   = blockIdx.x * 8;
    const int j0   = 16 * (q & 1) + 4 * kg + 2 * (q >> 1);  // cells j0, j0+1

    // ---- A-fragments (loop-invariant; shared by both groups) ----
    // Tile t4: gate rows gr = 16*t4+col, k = kg*8+e.
    // x-K-tile: kg0={Wih_hi,bias_hi@5}, kg1={Wih_hi,bias_lo@5}, kg2={Wih_lo}, kg3=0.
    short8 Ahh_hi[8], Ahh_lo[8], Ax[8];
#pragma unroll
    for (int t4 = 0; t4 < 8; ++t4) {
        const int gr = 16 * t4 + col;
#pragma unroll
        for (int e = 0; e < 8; ++e) {
            float wv = W_hh[gr * HH + kg * 8 + e];
            unsigned short hi = bf_rne(wv);
            Ahh_hi[t4][e] = (short)hi;
            Ahh_lo[t4][e] = (short)bf_rne(wv - bf_f32(hi));
        }
        float bias = b_ih[gr] + b_hh[gr];
        unsigned short bh_ = bf_rne(bias);
        unsigned short bl_ = bf_rne(bias - bf_f32(bh_));
        short8 v;
#pragma unroll
        for (int e = 0; e < 8; ++e) v[e] = 0;
        if (kg == 0 || kg == 1) {
#pragma unroll
            for (int e = 0; e < NIN; ++e) v[e] = (short)bf_rne(W_ih[gr * NIN + e]);
            v[5] = (short)((kg == 0) ? bh_ : bl_);
        } else if (kg == 2) {
#pragma unroll
            for (int e = 0; e < NIN; ++e) {
                float wv = W_ih[gr * NIN + e];
                unsigned short h2 = bf_rne(wv);
                v[e] = (short)bf_rne(wv - bf_f32(h2));
            }
        }
        Ax[t4] = v;
    }

    // ---- bh shfl sources (identical pattern for both groups) ----
    int src0, src1, src2, src3;
    {
        int s[4];
#pragma unroll
        for (int m = 0; m < 4; ++m) {
            const int jw  = 8 * kg + 2 * m;
            const int kgo = (jw & 15) >> 2;
            const int qp  = (jw >> 4) + 2 * ((jw >> 1) & 1);
            s[m] = 16 * kgo + 4 * qp + bloc;
        }
        src0 = s[0]; src1 = s[1]; src2 = s[2]; src3 = s[3];
    }

    // ---- per-lane bx-select constants ----
    const unsigned mskAll = (kg == 3) ? 0u : 0xFFFFFFFFu;
    const unsigned msk45  = (kg == 3) ? 0u : ((kg == 2) ? 0x0000FFFFu : 0xFFFFFFFFu);
    const bool isLo = (kg == 1);

    // ---- x pointers & t=0 values ----
    const float* pA = x + (size_t)(b0 + bloc) * TT * NIN;
    const float* pB = x + (size_t)(b0 + 4 + bloc) * TT * NIN;
    float xA[NIN], xB[NIN];
#pragma unroll
    for (int e = 0; e < NIN; ++e) { xA[e] = pA[e]; xB[e] = pB[e]; }

    unsigned int bhA0 = 0, bhA1 = 0, bhA2 = 0, bhA3 = 0;
    unsigned int bhB0 = 0, bhB1 = 0, bhB2 = 0, bhB3 = 0;
    float cA0 = 0.f, cA1 = 0.f, cB0 = 0.f, cB1 = 0.f;
    float hA0 = 0.f, hA1 = 0.f, hB0 = 0.f, hB1 = 0.f;
    const f32x4 z = {0.f, 0.f, 0.f, 0.f};

    // builds one group's bx fragment from 5 f32 x values (uniform, ~22 VALU)
    auto make_bx = [&](const float* xv) -> short8 {
        unsigned H01 = cvt_pk_bf16(xv[0], xv[1]);
        unsigned H23 = cvt_pk_bf16(xv[2], xv[3]);
        unsigned H45 = cvt_pk_bf16(xv[4], 1.0f);
        float l0 = xv[0] - __uint_as_float(H01 << 16);
        float l1 = xv[1] - __uint_as_float(H01 & 0xFFFF0000u);
        float l2 = xv[2] - __uint_as_float(H23 << 16);
        float l3 = xv[3] - __uint_as_float(H23 & 0xFFFF0000u);
        float l4 = xv[4] - __uint_as_float(H45 << 16);
        unsigned L01 = cvt_pk_bf16(l0, l1);
        unsigned L23 = cvt_pk_bf16(l2, l3);
        unsigned L45 = cvt_pk_bf16(l4, 1.0f);
        unsigned w0 = (isLo ? L01 : H01) & mskAll;
        unsigned w1 = (isLo ? L23 : H23) & mskAll;
        unsigned w2 = (isLo ? L45 : H45) & msk45;
        u32x4 u = {w0, w1, w2, 0u};
        return __builtin_bit_cast(short8, u);
    };

    // paired-rcp cell update; returns new h, updates c in place
    auto cell = [&](float gi, float gf, float gg, float go, float& c) -> float {
        float ea = __builtin_amdgcn_exp2f(-K1 * gi);
        float eb = __builtin_amdgcn_exp2f(-K1 * gf);
        float u = 1.f + ea, v = 1.f + eb;
        float r = __builtin_amdgcn_rcpf(u * v);
        float iv = v * r, fv = u * r;
        float eg = __builtin_amdgcn_exp2f(K2 * gg);
        float eo = __builtin_amdgcn_exp2f(-K1 * go);
        float u2 = 1.f + eg, v2 = 1.f + eo;
        float r2 = __builtin_amdgcn_rcpf(u2 * v2);
        float gv = 1.f - 2.f * (v2 * r2);     // tanh(gg)
        float ov = u2 * r2;                   // sigmoid(go)
        c = fmaf(fv, c, iv * gv);
        float et = __builtin_amdgcn_exp2f(K2 * c);
        float tc = 1.f - 2.f * __builtin_amdgcn_rcpf(1.f + et);
        return ov * tc;
    };

#pragma unroll 1
    for (int t = 0; t < TT; ++t) {
        // prefetch next x (both groups; uniform clamped offset)
        const size_t off = (size_t)((t + 1 < TT) ? (t + 1) : t) * NIN;
        float nA[NIN], nB[NIN];
#pragma unroll
        for (int e = 0; e < NIN; ++e) { nA[e] = pA[off + e]; nB[e] = pB[off + e]; }

        // B-fragments
        short8 bxA = make_bx(xA);
        short8 bxB = make_bx(xB);
        u32x4 ua = {bhA0, bhA1, bhA2, bhA3};
        u32x4 ub = {bhB0, bhB1, bhB2, bhB3};
        short8 bhA = __builtin_bit_cast(short8, ua);
        short8 bhB = __builtin_bit_cast(short8, ub);

        // 48 MFMAs: two independent sets of 8 x 3-chains
        f32x4 aA[8], aB[8];
#pragma unroll
        for (int t4 = 0; t4 < 8; ++t4) {
            aA[t4] = __builtin_amdgcn_mfma_f32_16x16x32_bf16(Ahh_lo[t4], bhA, z, 0, 0, 0);
            aB[t4] = __builtin_amdgcn_mfma_f32_16x16x32_bf16(Ahh_lo[t4], bhB, z, 0, 0, 0);
        }
#pragma unroll
        for (int t4 = 0; t4 < 8; ++t4) {
            aA[t4] = __builtin_amdgcn_mfma_f32_16x16x32_bf16(Ahh_hi[t4], bhA, aA[t4], 0, 0, 0);
            aB[t4] = __builtin_amdgcn_mfma_f32_16x16x32_bf16(Ahh_hi[t4], bhB, aB[t4], 0, 0, 0);
        }
#pragma unroll
        for (int t4 = 0; t4 < 8; ++t4) {
            aA[t4] = __builtin_amdgcn_mfma_f32_16x16x32_bf16(Ax[t4], bxA, aA[t4], 0, 0, 0);
            aB[t4] = __builtin_amdgcn_mfma_f32_16x16x32_bf16(Ax[t4], bxB, aB[t4], 0, 0, 0);
        }

        // gate select + cells, group A  (cells j0, j0+1 of batch b0+bloc)
        {
            float g[4][2];
#pragma unroll
            for (int G = 0; G < 4; ++G) {
                f32x4 tA = aA[2 * G], tB = aA[2 * G + 1];
                float s0 = jsel ? tB[0] : tA[0];
                float s1 = jsel ? tB[1] : tA[1];
                float s2 = jsel ? tB[2] : tA[2];
                float s3 = jsel ? tB[3] : tA[3];
                g[G][0] = rp ? s2 : s0;
                g[G][1] = rp ? s3 : s1;
            }
            hA0 = cell(g[0][0], g[1][0], g[2][0], g[3][0], cA0);
            hA1 = cell(g[0][1], g[1][1], g[2][1], g[3][1], cA1);
        }
        // group B
        {
            float g[4][2];
#pragma unroll
            for (int G = 0; G < 4; ++G) {
                f32x4 tA = aB[2 * G], tB = aB[2 * G + 1];
                float s0 = jsel ? tB[0] : tA[0];
                float s1 = jsel ? tB[1] : tA[1];
                float s2 = jsel ? tB[2] : tA[2];
                float s3 = jsel ? tB[3] : tA[3];
                g[G][0] = rp ? s2 : s0;
                g[G][1] = rp ? s3 : s1;
            }
            hB0 = cell(g[0][0], g[1][0], g[2][0], g[3][0], cB0);
            hB1 = cell(g[0][1], g[1][1], g[2][1], g[3][1], cB1);
        }

        // rebuild bh fragments for t+1 (4 shfl per group)
        unsigned int pkA = cvt_pk_bf16(hA0, hA1);
        unsigned int pkB = cvt_pk_bf16(hB0, hB1);
        bhA0 = (unsigned)__shfl((int)pkA, src0, 64);
        bhA1 = (unsigned)__shfl((int)pkA, src1, 64);
        bhA2 = (unsigned)__shfl((int)pkA, src2, 64);
        bhA3 = (unsigned)__shfl((int)pkA, src3, 64);
        bhB0 = (unsigned)__shfl((int)pkB, src0, 64);
        bhB1 = (unsigned)__shfl((int)pkB, src1, 64);
        bhB2 = (unsigned)__shfl((int)pkB, src2, 64);
        bhB3 = (unsigned)__shfl((int)pkB, src3, 64);

#pragma unroll
        for (int e = 0; e < NIN; ++e) { xA[e] = nA[e]; xB[e] = nB[e]; }
    }

    // ---- head ----
    const float w0 = W_fc[j0], w1 = W_fc[j0 + 1];
    float vA = hA0 * w0 + hA1 * w1;
    float vB = hB0 * w0 + hB1 * w1;
    vA += __shfl_xor(vA, 4);  vB += __shfl_xor(vB, 4);
    vA += __shfl_xor(vA, 8);  vB += __shfl_xor(vB, 8);
    vA += __shfl_xor(vA, 16); vB += __shfl_xor(vB, 16);
    vA += __shfl_xor(vA, 32); vB += __shfl_xor(vB, 32);
    if (lane < 4) {
        const float bias = b_fc[0];
        out[b0 + lane]     = vA + bias;
        out[b0 + 4 + lane] = vB + bias;
    }
}

extern "C" void kernel_launch(void* const* d_in, const int* in_sizes, int n_in,
                              void* d_out, int out_size, void* d_ws, size_t ws_size,
                              hipStream_t stream) {
    const float* x    = (const float*)d_in[0];
    const float* W_ih = (const float*)d_in[1];
    const float* W_hh = (const float*)d_in[2];
    const float* b_ih = (const float*)d_in[3];
    const float* b_hh = (const float*)d_in[4];
    const float* W_fc = (const float*)d_in[5];
    const float* b_fc = (const float*)d_in[6];
    float* out = (float*)d_out;

    lstm_ilp2<<<dim3(BB / 8), dim3(64), 0, stream>>>(
        x, W_ih, W_hh, b_ih, b_hh, W_fc, b_fc, out);
}

// Round 9
// 411.389 us; speedup vs baseline: 1.2007x; 1.2007x over previous
//
#include <hip/hip_runtime.h>

// LSTM round 9: R5 frame (8 batches/wave, 1024 blocks x 64 thr = 1 wave/SIMD,
// no LDS tiles, no barriers) + polynomial gates (NO v_exp):
//   tanh(x) ~= Pade[5/4] x(945+105t+t^2)/(945+420t+15t^2), t=x^2, clamp +-3.5
//   sigmoid(x) = 0.5 + 0.5*tanh(x/2)
// All denominators quad-rcp-paired: per lane-step 5 v_rcp total (was 32 transc).
// bx from per-lane L1-broadcast loads (no bpermute); h-pack via v_cvt_pk_bf16_f32.

typedef __attribute__((ext_vector_type(8))) short short8;
typedef __attribute__((ext_vector_type(4))) float f32x4;
typedef __attribute__((ext_vector_type(4))) unsigned int u32x4;

static constexpr int BB  = 8192;
static constexpr int TT  = 512;
static constexpr int NIN = 5;
static constexpr int HH  = 32;

__device__ __forceinline__ unsigned short bf_rne(float f) {
    unsigned int u = __float_as_uint(f);
    u = (u + 0x7FFFu + ((u >> 16) & 1u)) >> 16;
    return (unsigned short)u;
}
__device__ __forceinline__ float bf_f32(unsigned short h) {
    return __uint_as_float((unsigned int)h << 16);
}
__device__ __forceinline__ unsigned int cvt_pk_bf16(float a, float b) {
    unsigned int r;
    asm("v_cvt_pk_bf16_f32 %0, %1, %2" : "=v"(r) : "v"(a), "v"(b));
    return r;
}
// Pade[5/4] tanh pieces (input pre-clamped to +-3.5)
__device__ __forceinline__ void tpoly(float y, float& num, float& den) {
    float t = y * y;
    num = y * fmaf(t + 105.f, t, 945.f);
    den = fmaf(fmaf(15.f, t, 420.f), t, 945.f);
}
__device__ __forceinline__ float clamp35(float v) {
    return fminf(fmaxf(v, -3.5f), 3.5f);
}

__global__ __launch_bounds__(64, 1) void lstm_poly(
    const float* __restrict__ x,     // [B, T, 5]
    const float* __restrict__ W_ih,  // [128, 5]
    const float* __restrict__ W_hh,  // [128, 32]
    const float* __restrict__ b_ih,  // [128]
    const float* __restrict__ b_hh,  // [128]
    const float* __restrict__ W_fc,  // [1, 32]
    const float* __restrict__ b_fc,  // [1]
    float* __restrict__ out)         // [B]
{
    const int lane = threadIdx.x & 63;
    const int col  = lane & 15;      // MFMA col: batch (dup x2)
    const int kg   = lane >> 4;      // k-group
    const int b0   = blockIdx.x * 8;
    const int bloc = col & 7;        // local batch
    const bool jlow = (col < 8);
    const int jbase = 4 * kg + (jlow ? 0 : 16);

    // ---- A-fragments (loop-invariant registers) ----
    // Tile t4: gate rows gr = 16*t4 + col, k = kg*8 + e.
    // x-K-tile: kg0={Wih_hi,bias_hi@5}, kg1={Wih_hi,bias_lo@5}, kg2={Wih_lo}, kg3=0.
    short8 Ahh_hi[8], Ahh_lo[8], Ax[8];
#pragma unroll
    for (int t4 = 0; t4 < 8; ++t4) {
        const int gr = 16 * t4 + col;
#pragma unroll
        for (int e = 0; e < 8; ++e) {
            float wv = W_hh[gr * HH + kg * 8 + e];
            unsigned short hi = bf_rne(wv);
            Ahh_hi[t4][e] = (short)hi;
            Ahh_lo[t4][e] = (short)bf_rne(wv - bf_f32(hi));
        }
        float bias = b_ih[gr] + b_hh[gr];
        unsigned short bh_ = bf_rne(bias);
        unsigned short bl_ = bf_rne(bias - bf_f32(bh_));
        short8 v;
#pragma unroll
        for (int e = 0; e < 8; ++e) v[e] = 0;
        if (kg == 0 || kg == 1) {
#pragma unroll
            for (int e = 0; e < NIN; ++e) v[e] = (short)bf_rne(W_ih[gr * NIN + e]);
            v[5] = (short)((kg == 0) ? bh_ : bl_);
        } else if (kg == 2) {
#pragma unroll
            for (int e = 0; e < NIN; ++e) {
                float wv = W_ih[gr * NIN + e];
                unsigned short h2 = bf_rne(wv);
                v[e] = (short)bf_rne(wv - bf_f32(h2));
            }
        }
        Ax[t4] = v;
    }

    // ---- per-lane bx constants ----
    const bool isLo = (kg == 1);
    const unsigned mA  = (kg == 3) ? 0u : 0xFFFFFFFFu;
    const unsigned m45 = (kg == 3) ? 0u : ((kg == 2) ? 0x0000FFFFu : 0xFFFFFFFFu);

    // ---- bh shuffle sources (identical to R5, verified) ----
    const int srcA = 32 * (kg & 1) + bloc + 8 * (kg >> 1);
    const int srcB = srcA + 16;

    // ---- x: per-lane loads of own batch's row (8 lanes share addr -> broadcast) ----
    const float* px = x + (size_t)(b0 + bloc) * TT * NIN;
    float x0 = px[0], x1 = px[1], x2 = px[2], x3 = px[3], x4 = px[4];

    unsigned int bh0 = 0, bh1 = 0, bh2 = 0, bh3 = 0;
    float c0 = 0.f, c1 = 0.f, c2 = 0.f, c3 = 0.f;
    float h0 = 0.f, h1 = 0.f, h2 = 0.f, h3 = 0.f;
    const f32x4 z = {0.f, 0.f, 0.f, 0.f};

#pragma unroll 1
    for (int t = 0; t < TT; ++t) {
        // (1) prefetch next x (5 dwords; covered by this step's compute)
        const size_t off = (size_t)((t + 1 < TT) ? (t + 1) : t) * NIN;
        float n0 = px[off + 0], n1 = px[off + 1], n2 = px[off + 2],
              n3 = px[off + 3], n4 = px[off + 4];

        // (2) bx build in-registers (hi/lo split, slot5 = 1.0 for bias rows)
        unsigned H01 = cvt_pk_bf16(x0, x1);
        unsigned H23 = cvt_pk_bf16(x2, x3);
        unsigned H45 = cvt_pk_bf16(x4, 1.0f);
        float l0 = x0 - __uint_as_float(H01 << 16);
        float l1 = x1 - __uint_as_float(H01 & 0xFFFF0000u);
        float l2 = x2 - __uint_as_float(H23 << 16);
        float l3 = x3 - __uint_as_float(H23 & 0xFFFF0000u);
        float l4 = x4 - __uint_as_float(H45 << 16);
        unsigned L01 = cvt_pk_bf16(l0, l1);
        unsigned L23 = cvt_pk_bf16(l2, l3);
        unsigned L45 = cvt_pk_bf16(l4, 1.0f);
        unsigned w0 = (isLo ? L01 : H01) & mA;
        unsigned w1 = (isLo ? L23 : H23) & mA;
        unsigned w2 = (isLo ? L45 : H45) & m45;
        u32x4 bxu = {w0, w1, w2, 0u};
        short8 bx = __builtin_bit_cast(short8, bxu);
        u32x4 bhu = {bh0, bh1, bh2, bh3};
        short8 bh = __builtin_bit_cast(short8, bhu);

        // (3) 24 MFMAs: 8 independent 3-chains
        f32x4 acc[8];
#pragma unroll
        for (int t4 = 0; t4 < 8; ++t4)
            acc[t4] = __builtin_amdgcn_mfma_f32_16x16x32_bf16(Ahh_lo[t4], bh, z, 0, 0, 0);
#pragma unroll
        for (int t4 = 0; t4 < 8; ++t4)
            acc[t4] = __builtin_amdgcn_mfma_f32_16x16x32_bf16(Ahh_hi[t4], bh, acc[t4], 0, 0, 0);
#pragma unroll
        for (int t4 = 0; t4 < 8; ++t4)
            acc[t4] = __builtin_amdgcn_mfma_f32_16x16x32_bf16(Ax[t4], bx, acc[t4], 0, 0, 0);

        // (4) 4 cells, polynomial gates, quad-paired rcp
        float nc[4], dc[4], so[4];
#pragma unroll
        for (int r = 0; r < 4; ++r) {
            float gi = jlow ? acc[0][r] : acc[1][r];
            float gf = jlow ? acc[2][r] : acc[3][r];
            float gg = jlow ? acc[4][r] : acc[5][r];
            float go = jlow ? acc[6][r] : acc[7][r];

            float yi = clamp35(gi * 0.5f);
            float yf = clamp35(gf * 0.5f);
            float yo = clamp35(go * 0.5f);
            float yg = clamp35(gg);

            float ni, di, nf, df, ng, dg, no, dq;
            tpoly(yi, ni, di);
            tpoly(yf, nf, df);
            tpoly(yg, ng, dg);
            tpoly(yo, no, dq);

            float p01 = di * df, p23 = dg * dq;
            float rr = __builtin_amdgcn_rcpf(p01 * p23);
            float Ti = ni * ((df * p23) * rr);
            float Tf = nf * ((di * p23) * rr);
            float Tg = ng * ((p01 * dq) * rr);
            float To = no * ((p01 * dg) * rr);

            float si = fmaf(0.5f, Ti, 0.5f);
            float sf = fmaf(0.5f, Tf, 0.5f);
            so[r]    = fmaf(0.5f, To, 0.5f);

            float cc = (r == 0 ? c0 : r == 1 ? c1 : r == 2 ? c2 : c3);
            cc = fmaf(sf, cc, si * Tg);
            if (r == 0) c0 = cc; else if (r == 1) c1 = cc;
            else if (r == 2) c2 = cc; else c3 = cc;

            tpoly(clamp35(cc), nc[r], dc[r]);   // tanh(c): defer rcp to group2
        }
        {   // group2: quad-paired rcp for the 4 tanh(c) denominators
            float q01 = dc[0] * dc[1], q23 = dc[2] * dc[3];
            float rr = __builtin_amdgcn_rcpf(q01 * q23);
            h0 = so[0] * (nc[0] * ((dc[1] * q23) * rr));
            h1 = so[1] * (nc[1] * ((dc[0] * q23) * rr));
            h2 = so[2] * (nc[2] * ((q01 * dc[3]) * rr));
            h3 = so[3] * (nc[3] * ((q01 * dc[2]) * rr));
        }

        // (5) pack h; rebuild bh for t+1 with 4 shfl (R5-verified mapping)
        unsigned int p0 = cvt_pk_bf16(h0, h1);
        unsigned int p1 = cvt_pk_bf16(h2, h3);
        bh0 = (unsigned)__shfl((int)p0, srcA, 64);
        bh1 = (unsigned)__shfl((int)p1, srcA, 64);
        bh2 = (unsigned)__shfl((int)p0, srcB, 64);
        bh3 = (unsigned)__shfl((int)p1, srcB, 64);

        x0 = n0; x1 = n1; x2 = n2; x3 = n3; x4 = n4;
    }

    // ---- head: out[b] = sum_j h[b][j]*W_fc[j] + b_fc ----
    float v = h0 * W_fc[jbase + 0] + h1 * W_fc[jbase + 1]
            + h2 * W_fc[jbase + 2] + h3 * W_fc[jbase + 3];
    v += __shfl_xor(v, 8);    // combine j-low/j-high
    v += __shfl_xor(v, 16);   // combine kg
    v += __shfl_xor(v, 32);
    if (lane < 8) out[b0 + lane] = v + b_fc[0];
}

extern "C" void kernel_launch(void* const* d_in, const int* in_sizes, int n_in,
                              void* d_out, int out_size, void* d_ws, size_t ws_size,
                              hipStream_t stream) {
    const float* x    = (const float*)d_in[0];
    const float* W_ih = (const float*)d_in[1];
    const float* W_hh = (const float*)d_in[2];
    const float* b_ih = (const float*)d_in[3];
    const float* b_hh = (const float*)d_in[4];
    const float* W_fc = (const float*)d_in[5];
    const float* b_fc = (const float*)d_in[6];
    float* out = (float*)d_out;

    lstm_poly<<<dim3(BB / 8), dim3(64), 0, stream>>>(
        x, W_ih, W_hh, b_ih, b_hh, W_fc, b_fc, out);
}

// Round 10
// 270.129 us; speedup vs baseline: 1.8285x; 1.5229x over previous
//
#include <hip/hip_runtime.h>

// LSTM round 10: R5 frame (8 batches/wave, 1024 waves = 1/SIMD, no LDS tiles,
// no barriers) + fp16 single-precision weights/h/x (no hi/lo; 16 MFMA, 2-chain)
// + software-pipelined x-projection: accN(t+1) = mfma(Ax, bx(t+1), 0) issued
// during step t's cell phase, so step t+1 starts at chain-2 mfma(Ahh, bh, accN).
// Bias split hi/lo into spare K-slots 5/6 (exact). Cells = R5 exp/rcp form.

typedef __attribute__((ext_vector_type(8))) _Float16 half8;
typedef __attribute__((ext_vector_type(4))) float f32x4;
typedef __attribute__((ext_vector_type(4))) unsigned int u32x4;

static constexpr int BB  = 8192;
static constexpr int TT  = 512;
static constexpr int NIN = 5;
static constexpr int HH  = 32;

__device__ __forceinline__ unsigned short f16b(float f) {
    _Float16 h = (_Float16)f;                       // RNE
    return __builtin_bit_cast(unsigned short, h);
}
__device__ __forceinline__ float fast_sigmoid(float x) {
    float e = __builtin_amdgcn_exp2f(-1.4426950408889634f * x);
    return __builtin_amdgcn_rcpf(1.0f + e);
}
__device__ __forceinline__ float fast_tanh(float x) {
    float e = __builtin_amdgcn_exp2f(2.8853900817779268f * x);
    return 1.0f - 2.0f * __builtin_amdgcn_rcpf(1.0f + e);
}

__global__ __launch_bounds__(64) void lstm_f16(
    const float* __restrict__ x,     // [B, T, 5]
    const float* __restrict__ W_ih,  // [128, 5]
    const float* __restrict__ W_hh,  // [128, 32]
    const float* __restrict__ b_ih,  // [128]
    const float* __restrict__ b_hh,  // [128]
    const float* __restrict__ W_fc,  // [1, 32]
    const float* __restrict__ b_fc,  // [1]
    float* __restrict__ out)         // [B]
{
    const int lane = threadIdx.x & 63;
    const int col  = lane & 15;      // batch (dup x2)
    const int kg   = lane >> 4;      // k-group
    const int b0   = blockIdx.x * 8;
    const int bloc = col & 7;
    const bool jlow = (col < 8);
    const int jbase = 4 * kg + (jlow ? 0 : 16);

    // ---- A-fragments (loop-invariant). Tile t4: gate rows gr=16*t4+col,
    // k=kg*8+e. Ahh: W_hh@f16. Ax (kg0 only): slots0-4=W_ih@f16,
    // slot5=bias_hi@f16, slot6=bias_lo@f16, slot7=0; kg1-3 zero.
    half8 Ahh[8], Ax[8];
#pragma unroll
    for (int t4 = 0; t4 < 8; ++t4) {
        const int gr = 16 * t4 + col;
#pragma unroll
        for (int e = 0; e < 8; ++e)
            Ahh[t4][e] = (_Float16)W_hh[gr * HH + kg * 8 + e];
        half8 v;
#pragma unroll
        for (int e = 0; e < 8; ++e) v[e] = (_Float16)0.f;
        if (kg == 0) {
#pragma unroll
            for (int e = 0; e < NIN; ++e) v[e] = (_Float16)W_ih[gr * NIN + e];
            float bias = b_ih[gr] + b_hh[gr];
            _Float16 bh_ = (_Float16)bias;
            v[5] = bh_;
            v[6] = (_Float16)(bias - (float)bh_);
        }
        Ax[t4] = v;
    }

    // ---- bh shuffle sources (R5-verified mapping; 16-bit element layout
    // identical between bf16 and f16 fragments) ----
    const int srcA = 32 * (kg & 1) + bloc + 8 * (kg >> 1);
    const int srcB = srcA + 16;

    // bx lane mask: only kg==0 carries x
    const bool xk = (kg == 0);

    // ---- x stream: per-lane loads of own batch row (8-lane broadcast) ----
    const float* px = x + (size_t)(b0 + bloc) * TT * NIN;
    float x0 = px[0], x1 = px[1], x2 = px[2], x3 = px[3], x4 = px[4];

    unsigned int bh0 = 0, bh1 = 0, bh2 = 0, bh3 = 0;   // h^T frag (h=0)
    float c0 = 0.f, c1 = 0.f, c2 = 0.f, c3 = 0.f;
    float h0 = 0.f, h1 = 0.f, h2 = 0.f, h3 = 0.f;
    const f32x4 z = {0.f, 0.f, 0.f, 0.f};

    auto make_bx = [&](float v0, float v1, float v2, float v3, float v4) -> half8 {
        unsigned w0 = (unsigned)f16b(v0) | ((unsigned)f16b(v1) << 16);
        unsigned w1 = (unsigned)f16b(v2) | ((unsigned)f16b(v3) << 16);
        unsigned w2 = (unsigned)f16b(v4) | (0x3C00u << 16);   // slot5 = 1.0
        unsigned w3 = 0x00003C00u;                            // slot6 = 1.0
        u32x4 u = {xk ? w0 : 0u, xk ? w1 : 0u, xk ? w2 : 0u, xk ? w3 : 0u};
        return __builtin_bit_cast(half8, u);
    };

    // ---- prologue: chain-1 for t=0 ----
    f32x4 accN[8];
    {
        half8 bx0 = make_bx(x0, x1, x2, x3, x4);
#pragma unroll
        for (int t4 = 0; t4 < 8; ++t4)
            accN[t4] = __builtin_amdgcn_mfma_f32_16x16x32_f16(Ax[t4], bx0, z, 0, 0, 0);
    }

#pragma unroll 1
    for (int t = 0; t < TT; ++t) {
        // (1) prefetch x(t+1)
        const size_t off = (size_t)((t + 1 < TT) ? (t + 1) : t) * NIN;
        float n0 = px[off + 0], n1 = px[off + 1], n2 = px[off + 2],
              n3 = px[off + 3], n4 = px[off + 4];

        // (2) chain-2: acc = Ahh*bh + accN   (8 MFMA, step head)
        u32x4 bhu = {bh0, bh1, bh2, bh3};
        half8 bh = __builtin_bit_cast(half8, bhu);
        f32x4 acc[8];
#pragma unroll
        for (int t4 = 0; t4 < 8; ++t4)
            acc[t4] = __builtin_amdgcn_mfma_f32_16x16x32_f16(Ahh[t4], bh, accN[t4], 0, 0, 0);

        // (3) chain-1 for t+1 (independent; fills cell-phase matrix idle)
        half8 bxn = make_bx(n0, n1, n2, n3, n4);
#pragma unroll
        for (int t4 = 0; t4 < 8; ++t4)
            accN[t4] = __builtin_amdgcn_mfma_f32_16x16x32_f16(Ax[t4], bxn, z, 0, 0, 0);

        // (4) 4 cells (R5 exp/rcp form)
#pragma unroll
        for (int r = 0; r < 4; ++r) {
            float gi = jlow ? acc[0][r] : acc[1][r];
            float gf = jlow ? acc[2][r] : acc[3][r];
            float gg = jlow ? acc[4][r] : acc[5][r];
            float go = jlow ? acc[6][r] : acc[7][r];
            float iv = fast_sigmoid(gi);
            float fv = fast_sigmoid(gf);
            float gv = fast_tanh(gg);
            float ov = fast_sigmoid(go);
            float cc = (r == 0 ? c0 : r == 1 ? c1 : r == 2 ? c2 : c3);
            cc = fmaf(fv, cc, iv * gv);
            float hh = ov * fast_tanh(cc);
            if (r == 0) { c0 = cc; h0 = hh; }
            else if (r == 1) { c1 = cc; h1 = hh; }
            else if (r == 2) { c2 = cc; h2 = hh; }
            else { c3 = cc; h3 = hh; }
        }

        // (5) pack h -> f16 pairs; rebuild bh for t+1 (4 shfl, R5 mapping)
        unsigned int p0 = (unsigned)f16b(h0) | ((unsigned)f16b(h1) << 16);
        unsigned int p1 = (unsigned)f16b(h2) | ((unsigned)f16b(h3) << 16);
        bh0 = (unsigned)__shfl((int)p0, srcA, 64);
        bh1 = (unsigned)__shfl((int)p1, srcA, 64);
        bh2 = (unsigned)__shfl((int)p0, srcB, 64);
        bh3 = (unsigned)__shfl((int)p1, srcB, 64);

        x0 = n0; x1 = n1; x2 = n2; x3 = n3; x4 = n4;
    }

    // ---- head: out[b] = sum_j h[b][j]*W_fc[j] + b_fc ----
    float v = h0 * W_fc[jbase + 0] + h1 * W_fc[jbase + 1]
            + h2 * W_fc[jbase + 2] + h3 * W_fc[jbase + 3];
    v += __shfl_xor(v, 8);
    v += __shfl_xor(v, 16);
    v += __shfl_xor(v, 32);
    if (lane < 8) out[b0 + lane] = v + b_fc[0];
}

extern "C" void kernel_launch(void* const* d_in, const int* in_sizes, int n_in,
                              void* d_out, int out_size, void* d_ws, size_t ws_size,
                              hipStream_t stream) {
    const float* x    = (const float*)d_in[0];
    const float* W_ih = (const float*)d_in[1];
    const float* W_hh = (const float*)d_in[2];
    const float* b_ih = (const float*)d_in[3];
    const float* b_hh = (const float*)d_in[4];
    const float* W_fc = (const float*)d_in[5];
    const float* b_fc = (const float*)d_in[6];
    float* out = (float*)d_out;

    lstm_f16<<<dim3(BB / 8), dim3(64), 0, stream>>>(
        x, W_ih, W_hh, b_ih, b_hh, W_fc, b_fc, out);
}